// Round 10
// baseline (353.381 us; speedup 1.0000x reference)
//
#include <hip/hip_runtime.h>
#include <hip/hip_bf16.h>
#include <stdint.h>

// HyperbolicAttention MI355X implementation.
// B=2, N=4096, D_IN=256, UNITS=512, H=8, depth=64.
// Round 10: attention = R9 inner math (32x32 MFMA, in-register P via permlane32_swap)
// with 64 q per wave (K/V/k2 shared across 2 strips), j-split x4 (16 jc/block,
// grid 1024), bf16 partials, jc-loop unrolled x2 (compile-time buffer select).

typedef __attribute__((ext_vector_type(8))) short short8;
typedef __attribute__((ext_vector_type(4))) float f32x4;
typedef __attribute__((ext_vector_type(16))) float f32x16;
typedef __attribute__((ext_vector_type(2))) unsigned int u32x2;
typedef __attribute__((ext_vector_type(4))) unsigned int u32x4;

#define DEVFN static __device__ __forceinline__

DEVFN unsigned short f2bf(float f) {
  unsigned u = __float_as_uint(f);
  u += 0x7FFFu + ((u >> 16) & 1u);   // RNE
  return (unsigned short)(u >> 16);
}

DEVFN void mfma16(f32x4& d, short8 a, short8 b) {
  d = __builtin_amdgcn_mfma_f32_16x16x32_bf16(a, b, d, 0, 0, 0);
}
DEVFN void mfma32(f32x16& d, short8 a, short8 b) {
  d = __builtin_amdgcn_mfma_f32_32x32x16_bf16(a, b, d, 0, 0, 0);
}

DEVFN void gload_lds16(const void* g, void* l) {
  __builtin_amdgcn_global_load_lds((__attribute__((address_space(1))) void*)g,
                                   (__attribute__((address_space(3))) void*)l, 16, 0, 0);
}

// ---------------- weight convert + transpose to BT layout (bf16) ----------------
__global__ __launch_bounds__(256) void wconv_kernel(const float* Wq, const float* Wk,
                                                    const float* Wv, const float* Wo,
                                                    unsigned short* wqkvT, unsigned short* woT) {
  int t = blockIdx.x * 256 + threadIdx.x;
  if (t < 1536 * 256) {
    int nn = t >> 8, kk = t & 255;
    int which = nn >> 9, n2 = nn & 511;
    const float* W = (which == 0) ? Wq : (which == 1) ? Wk : Wv;
    wqkvT[t] = f2bf(W[kk * 512 + n2]);
  }
  int t2 = t - 1536 * 256;
  if (t2 >= 0 && t2 < 512 * 512) {
    int nn = t2 >> 9, kk = t2 & 511;
    woT[t2] = f2bf(Wo[kk * 512 + nn]);
  }
}

// ---------------- tangent = logmap0(inputs), bf16 [8192][256] ----------------
__global__ __launch_bounds__(256) void tangent_kernel(const float* x, unsigned short* tang) {
  const int row = blockIdx.x;
  const int tid = threadIdx.x;
  float v = x[(size_t)row * 256 + tid];
  float ss = v * v;
  #pragma unroll
  for (int m = 1; m <= 32; m <<= 1) ss += __shfl_xor(ss, m, 64);
  __shared__ __align__(16) float red[4];
  if ((tid & 63) == 0) red[tid >> 6] = ss;
  __syncthreads();
  float tot = (red[0] + red[1]) + (red[2] + red[3]);
  float n = fmaxf(sqrtf(tot), 1e-7f);
  float arg = fminf(n, 1.0f - 1e-5f);
  float scale = atanhf(arg) / n;
  tang[(size_t)row * 256 + tid] = f2bf(v * scale);
}

// ---------------- GEMM: C[M][N] f32 = A[M][K]bf16 @ B, B given as BT[N][K]bf16 ----------------
__global__ __launch_bounds__(256) void gemm_bt(const unsigned short* A, const unsigned short* BT,
                                               float* C, int M, int N, int K, int NB) {
  __shared__ __align__(16) unsigned short As[2][64 * 64];
  __shared__ __align__(16) unsigned short Bs[2][64 * 64];
  const int tid = threadIdx.x;
  const int l = tid & 63, w = tid >> 6;
  const int g = l >> 4, i = l & 15;
  const int bm = blockIdx.x / NB, bn = blockIdx.x % NB;
  const int m0 = bm << 6, n0 = bn << 6;
  const int wm = w >> 1, wn = w & 1;
  f32x4 acc[2][2] = {};

  const int NK = K >> 6;
  auto stage = [&](int kc, int bb) {
    const int kb = kc << 6;
    #pragma unroll
    for (int inst = 0; inst < 2; ++inst) {
      int o = (w << 11) + (inst << 10) + (l << 4);
      int row = o >> 7;
      int gG = ((o >> 4) & 7) ^ (row & 7);
      gload_lds16(A + ((size_t)(m0 + row) * K + kb + gG * 8),
                  (char*)&As[bb][0] + (w << 11) + (inst << 10));
      gload_lds16(BT + ((size_t)(n0 + row) * K + kb + gG * 8),
                  (char*)&Bs[bb][0] + (w << 11) + (inst << 10));
    }
  };
  stage(0, 0);
  __syncthreads();
  for (int kc = 0; kc < NK; ++kc) {
    const int bb = kc & 1;
    if (kc + 1 < NK) stage(kc + 1, bb ^ 1);
    #pragma unroll
    for (int hh = 0; hh < 2; ++hh) {
      short8 af[2], bf[2];
      #pragma unroll
      for (int mt = 0; mt < 2; ++mt) {
        int row = (wm << 5) + (mt << 4) + i;
        af[mt] = *(const short8*)((const char*)&As[bb][0] + (row << 7) +
                                  ((((hh << 2) + g) ^ (row & 7)) << 4));
      }
      #pragma unroll
      for (int nt = 0; nt < 2; ++nt) {
        int row = (wn << 5) + (nt << 4) + i;
        bf[nt] = *(const short8*)((const char*)&Bs[bb][0] + (row << 7) +
                                  ((((hh << 2) + g) ^ (row & 7)) << 4));
      }
      #pragma unroll
      for (int mt = 0; mt < 2; ++mt)
        #pragma unroll
        for (int nt = 0; nt < 2; ++nt)
          mfma16(acc[mt][nt], af[mt], bf[nt]);
    }
    __syncthreads();
  }
  #pragma unroll
  for (int mt = 0; mt < 2; ++mt)
    #pragma unroll
    for (int nt = 0; nt < 2; ++nt)
      #pragma unroll
      for (int r = 0; r < 4; ++r) {
        int row = m0 + (wm << 5) + (mt << 4) + (g << 2) + r;
        int col = n0 + (wn << 5) + (nt << 4) + i;
        C[(size_t)row * N + col] = acc[mt][nt][r];
      }
}

// ---------------- per-head hyperbolic maps ----------------
__global__ __launch_bounds__(256) void hyp_kernel(const float* qkv, unsigned short* qh,
                                                  unsigned short* kh, unsigned short* vT,
                                                  float* k2lT) {
  __shared__ __align__(16) unsigned short vt_t[64][72];
  const int tid = threadIdx.x;
  const int l = tid & 63, w = tid >> 6;
  const int bh = blockIdx.x & 15, nt = blockIdx.x >> 4;
  const int b = bh >> 3, h = bh & 7;
  const int n0 = nt << 6;
  const int d = l;
  for (int r = 0; r < 16; ++r) {
    int n = n0 + w * 16 + r;
    size_t base = (size_t)(b * 4096 + n) * 1536 + h * 64 + d;
    float qv = qkv[base], kv = qkv[base + 512], vv = qkv[base + 1024];
    float sq = qv * qv, sk = kv * kv, sv = vv * vv;
    #pragma unroll
    for (int m = 1; m <= 32; m <<= 1) {
      sq += __shfl_xor(sq, m, 64);
      sk += __shfl_xor(sk, m, 64);
      sv += __shfl_xor(sv, m, 64);
    }
    float nq = fmaxf(sqrtf(sq), 1e-7f);
    float qs = tanhf(nq) / nq;
    float nk = fmaxf(sqrtf(sk), 1e-7f);
    float tk = tanhf(nk);
    float ks = tk / nk;
    float nv = fmaxf(sqrtf(sv), 1e-7f);
    float vs = atanhf(fminf(nv, 1.0f - 1e-5f)) / nv;
    size_t ob = (size_t)(b * 4096 + n) * 512 + h * 64 + d;
    qh[ob] = f2bf(qv * qs);
    kh[ob] = f2bf(kv * ks);
    if (d == 0) k2lT[(size_t)bh * 4096 + n] = tk * tk * 0.125f * 1.4426950408889634f;
    vt_t[d][w * 16 + r] = f2bf(vv * vs);
  }
  __syncthreads();
  const int dd = tid >> 2, p = tid & 3;
  u32x4 a0 = *(const u32x4*)&vt_t[dd][p * 16];
  u32x4 a1 = *(const u32x4*)&vt_t[dd][p * 16 + 8];
  size_t vb = (size_t)(bh * 64 + dd) * 4096 + n0 + p * 16;
  *(u32x4*)(vT + vb) = a0;
  *(u32x4*)(vT + vb + 8) = a1;
}

// ---------------- attention (32x32 MFMA, 64q/wave, in-register P, j-split x4) ----------------
// Grid 1024 = (bh[4b], qt[4b], quarter[2b]). 256 threads = 4 waves; wave w owns TWO
// 32-q strips q = qt*256 + w*64 + s*32 + (lane&31). Block does j in [quarter*1024, +1024),
// 16 jc of 64 j. K/V staged global->LDS dbuf (32KB, XOR-swizzled via source); K/V/k2
// fragments SHARED across the 2 strips (halves per-q LDS + addr cost). Swapped QK at
// 32x32x16 (C: col q = lane&31, row j_local = (reg&3)+8*(reg>>2)+4*hi). PV B-frag via
// 8 cvt_pk + 4 permlane32_swap (T12). Denominator = f32 sum + shfl_xor(32).
// Unnormalized partial O (bf16) + den (f32) out; combine merges 4 quarters.
__global__ __launch_bounds__(256, 3) void attn_kernel(const unsigned short* __restrict__ qhG,
                                                      const unsigned short* __restrict__ khG,
                                                      const unsigned short* __restrict__ vTG,
                                                      const float* __restrict__ k2lG,
                                                      unsigned short* __restrict__ opart,
                                                      float* __restrict__ denpart) {
  __shared__ __align__(16) unsigned short Kbuf[2][64 * 64];
  __shared__ __align__(16) unsigned short Vbuf[2][64 * 64];

  const int tid = threadIdx.x;
  const int lane = tid & 63, w = tid >> 6;
  const int l31 = lane & 31, hi = lane >> 5;
  const int p = blockIdx.x;
  const int bh = p & 15, qt = (p >> 4) & 15, quarter = p >> 8;
  const int b = bh >> 3, h = bh & 7;
  const int qw = qt * 256 + w * 64;
  const int j0 = quarter << 10;

  const float CQK = 0.36067376022224087f;  // 0.25 * log2(e)

  // resident Q B-frags: [strip][kk], col q = qw + s*32 + l31, k-elem d = kk*16 + hi*8 + e
  short8 qf[2][4];
  #pragma unroll
  for (int s = 0; s < 2; ++s)
    #pragma unroll
    for (int kk = 0; kk < 4; ++kk)
      qf[s][kk] = *(const short8*)(qhG + (size_t)(b * 4096 + qw + s * 32 + l31) * 512 +
                                   h * 64 + kk * 16 + hi * 8);

  f32x16 acc[2][2] = {};   // [s][dh]: O^T rows d = dh*32 + (reg&3)+8*(reg>>2)+4*hi, col q
  float den[2] = {0.f, 0.f};

  auto stage = [&](int jc2, int bb) {
    const int jb = jc2 << 6;
    #pragma unroll
    for (int inst = 0; inst < 2; ++inst) {
      int o = (w << 11) + (inst << 10) + (lane << 4);
      int row = o >> 7;
      int gG = ((o >> 4) & 7) ^ (row & 7);
      gload_lds16(khG + ((size_t)(b * 4096 + j0 + jb + row) * 512 + h * 64 + gG * 8),
                  (char*)&Kbuf[bb][0] + o);
      gload_lds16(vTG + ((size_t)(bh * 64 + row) * 4096 + j0 + jb + gG * 8),
                  (char*)&Vbuf[bb][0] + o);
    }
  };

  const float* k2b = k2lG + (size_t)bh * 4096 + j0;

  auto compute = [&](int jc, int bb) {
    const char* Kb = (const char*)&Kbuf[bb][0];
    const char* Vb = (const char*)&Vbuf[bb][0];
    #pragma unroll
    for (int js = 0; js < 2; ++js) {
      // shared K frags: A rows j = js*32 + l31, k d = kk*16 + hi*8 + e
      const int krow = js * 32 + l31;
      const int ksw = krow & 7;
      short8 kf[4];
      #pragma unroll
      for (int kk = 0; kk < 4; ++kk)
        kf[kk] = *(const short8*)(Kb + (krow << 7) + ((((kk << 1) + hi) ^ ksw) << 4));
      // shared V frags: A rows d = dh*32 + l31, k j = js*32 + kc2*16 + hi*8 + e
      short8 vf[2][2];
      #pragma unroll
      for (int kc2 = 0; kc2 < 2; ++kc2)
        #pragma unroll
        for (int dh = 0; dh < 2; ++dh) {
          const int vrow = dh * 32 + l31;
          const int gv = ((js << 2) + (kc2 << 1) + hi) ^ (vrow & 7);
          vf[kc2][dh] = *(const short8*)(Vb + (vrow << 7) + (gv << 4));
        }
      // shared k2: j_local(reg) = (reg&3) + 8*(reg>>2) + 4*hi
      const float* k2p = k2b + (jc << 6) + js * 32 + hi * 4;
      f32x4 k2v[4];
      #pragma unroll
      for (int t = 0; t < 4; ++t) k2v[t] = *(const f32x4*)(k2p + t * 8);

      #pragma unroll
      for (int s = 0; s < 2; ++s) {
        f32x16 S = {};
        #pragma unroll
        for (int kk = 0; kk < 4; ++kk) mfma32(S, kf[kk], qf[s][kk]);
        float pr[16];
        float dsum = 0.f;
        #pragma unroll
        for (int t = 0; t < 4; ++t)
          #pragma unroll
          for (int e = 0; e < 4; ++e) {
            float v = __builtin_amdgcn_exp2f(fmaf(S[t * 4 + e], CQK, -k2v[t][e]));
            pr[t * 4 + e] = v;
            dsum += v;
          }
        den[s] += dsum;
        unsigned wds[8];
        #pragma unroll
        for (int m = 0; m < 8; ++m) {
          __hip_bfloat162 t2 = __float22bfloat162_rn(make_float2(pr[2 * m], pr[2 * m + 1]));
          __builtin_memcpy(&wds[m], &t2, 4);
        }
        u32x2 s0 = __builtin_amdgcn_permlane32_swap(wds[0], wds[2], false, false);
        u32x2 s1 = __builtin_amdgcn_permlane32_swap(wds[1], wds[3], false, false);
        u32x2 s2 = __builtin_amdgcn_permlane32_swap(wds[4], wds[6], false, false);
        u32x2 s3 = __builtin_amdgcn_permlane32_swap(wds[5], wds[7], false, false);
        unsigned fw[2][4];
        fw[0][0] = s0[0]; fw[0][1] = s1[0]; fw[0][2] = s0[1]; fw[0][3] = s1[1];
        fw[1][0] = s2[0]; fw[1][1] = s3[0]; fw[1][2] = s2[1]; fw[1][3] = s3[1];
        #pragma unroll
        for (int kc2 = 0; kc2 < 2; ++kc2) {
          u32x4 t4;
          t4[0] = fw[kc2][0];
          t4[1] = fw[kc2][1];
          t4[2] = fw[kc2][2];
          t4[3] = fw[kc2][3];
          short8 pf;
          __builtin_memcpy(&pf, &t4, 16);
          #pragma unroll
          for (int dh = 0; dh < 2; ++dh)
            mfma32(acc[s][dh], vf[kc2][dh], pf);
        }
      }
    }
  };

  stage(0, 0);
  __syncthreads();
  for (int jc = 0; jc < 16; jc += 2) {
    stage(jc + 1, 1);
    compute(jc, 0);
    __syncthreads();
    if (jc + 2 < 16) stage(jc + 2, 0);
    compute(jc + 1, 1);
    __syncthreads();
  }

  #pragma unroll
  for (int s = 0; s < 2; ++s) den[s] += __shfl_xor(den[s], 32, 64);

  // partial epilogue: unnormalized O (bf16, paired stores) + row denominators (f32)
  unsigned short* ob = opart + (size_t)quarter * (8192 * 512);
  #pragma unroll
  for (int s = 0; s < 2; ++s) {
    const size_t obase = (size_t)(b * 4096 + qw + s * 32 + l31) * 512 + h * 64;
    #pragma unroll
    for (int dh = 0; dh < 2; ++dh)
      #pragma unroll
      for (int rp = 0; rp < 8; ++rp) {
        const int reg0 = rp * 2;
        const int d = dh * 32 + (reg0 & 3) + 8 * (reg0 >> 2) + 4 * hi;
        __hip_bfloat162 t2 = __float22bfloat162_rn(
            make_float2(acc[s][dh][reg0], acc[s][dh][reg0 + 1]));
        unsigned pk;
        __builtin_memcpy(&pk, &t2, 4);
        *(unsigned*)(ob + obase + d) = pk;
      }
  }
  if (lane < 32) {
    denpart[quarter * 65536 + bh * 4096 + qw + l31] = den[0];
    denpart[quarter * 65536 + bh * 4096 + qw + 32 + l31] = den[1];
  }
}

// ---------------- combine: ctx = (sum of 4 partial O) / (sum of 4 den), bf16 ----------------
__global__ __launch_bounds__(256) void combine_kernel(const unsigned short* __restrict__ opart,
                                                      const float* __restrict__ denpart,
                                                      unsigned short* __restrict__ ctx) {
  const int idx = blockIdx.x * 256 + threadIdx.x;   // 524288 groups of 8 bf16
  const int row = idx >> 6;
  const int d0 = (idx & 63) << 3;
  const int b = row >> 12, q = row & 4095;
  const int bh = b * 8 + (d0 >> 6);
  float den = 0.f;
  #pragma unroll
  for (int part = 0; part < 4; ++part)
    den += denpart[part * 65536 + bh * 4096 + q];
  const float inv = 1.0f / den;
  const size_t off = (size_t)row * 512 + d0;
  float s[8] = {};
  #pragma unroll
  for (int part = 0; part < 4; ++part) {
    u32x4 v = *(const u32x4*)(opart + part * (size_t)(8192 * 512) + off);
    #pragma unroll
    for (int j = 0; j < 4; ++j) {
      s[2 * j] += __uint_as_float(v[j] << 16);
      s[2 * j + 1] += __uint_as_float(v[j] & 0xFFFF0000u);
    }
  }
  u32x4 o;
  #pragma unroll
  for (int j = 0; j < 4; ++j) {
    __hip_bfloat162 t2 = __float22bfloat162_rn(make_float2(s[2 * j] * inv, s[2 * j + 1] * inv));
    unsigned pk;
    __builtin_memcpy(&pk, &t2, 4);
    o[j] = pk;
  }
  *(u32x4*)(ctx + off) = o;
}

// ---------------- final expmap0 over 512-dim rows ----------------
__global__ __launch_bounds__(256) void final_kernel(const float* xin, float* out) {
  const int row = blockIdx.x;
  const int tid = threadIdx.x;
  const float* xr = xin + (size_t)row * 512;
  float v0 = xr[tid], v1 = xr[tid + 256];
  float ss = v0 * v0 + v1 * v1;
  #pragma unroll
  for (int m = 1; m <= 32; m <<= 1) ss += __shfl_xor(ss, m, 64);
  __shared__ __align__(16) float red[4];
  if ((tid & 63) == 0) red[tid >> 6] = ss;
  __syncthreads();
  float tot = (red[0] + red[1]) + (red[2] + red[3]);
  float n = fmaxf(sqrtf(tot), 1e-7f);
  float sc = tanhf(n) / n;
  out[(size_t)row * 512 + tid] = v0 * sc;
  out[(size_t)row * 512 + tid + 256] = v1 * sc;
}

// ---------------- launch ----------------
extern "C" void kernel_launch(void* const* d_in, const int* in_sizes, int n_in,
                              void* d_out, int out_size, void* d_ws, size_t ws_size,
                              hipStream_t stream) {
  const float* inputs = (const float*)d_in[0];
  const float* Wq = (const float*)d_in[1];
  const float* Wk = (const float*)d_in[2];
  const float* Wv = (const float*)d_in[3];
  const float* Wo = (const float*)d_in[4];
  float* out = (float*)d_out;
  char* ws = (char*)d_ws;

  // workspace layout (~79.25 MB peak):
  //  [0,48M):  qkv f32 [8192][1536] during proj; dead after hyp. Reuse:
  //    ctx bf16 @0 (8M); opart bf16 [4][8192][512] @8M (32M, dead after combine);
  //    out_pre f32 @8M (16M, written by gemm2 after combine over dead opart)
  //  [48M): k2lT f32 (256K); [49M): denpart f32 [4][65536] (1M)
  //  [53M): wqkvT (0.75M); [54M): woT (0.5M)
  //  [55M): qh (8M); [63M): kh (8M); [71M): vT (8M)    (tang @48M during proj)
  float* qkv            = (float*)(ws);
  unsigned short* ctx   = (unsigned short*)(ws);
  unsigned short* opart = (unsigned short*)(ws + ((size_t)8 << 20));
  float* out_pre        = (float*)(ws + ((size_t)8 << 20));
  unsigned short* tang  = (unsigned short*)(ws + ((size_t)48 << 20));
  float* k2lT           = (float*)(ws + ((size_t)48 << 20));
  float* denpart        = (float*)(ws + ((size_t)49 << 20));
  unsigned short* wqkvT = (unsigned short*)(ws + ((size_t)53 << 20));
  unsigned short* woT   = (unsigned short*)(ws + ((size_t)54 << 20));
  unsigned short* qh    = (unsigned short*)(ws + ((size_t)55 << 20));
  unsigned short* kh    = (unsigned short*)(ws + ((size_t)63 << 20));
  unsigned short* vT    = (unsigned short*)(ws + ((size_t)71 << 20));

  wconv_kernel<<<2560, 256, 0, stream>>>(Wq, Wk, Wv, Wo, wqkvT, woT);
  tangent_kernel<<<8192, 256, 0, stream>>>(inputs, tang);
  gemm_bt<<<128 * 24, 256, 0, stream>>>(tang, wqkvT, qkv, 8192, 1536, 256, 24);
  hyp_kernel<<<1024, 256, 0, stream>>>(qkv, qh, kh, vT, k2lT);
  attn_kernel<<<1024, 256, 0, stream>>>(qh, kh, vT, k2lT, opart, denpart);
  combine_kernel<<<2048, 256, 0, stream>>>(opart, denpart, ctx);
  gemm_bt<<<128 * 8, 256, 0, stream>>>(ctx, woT, out_pre, 8192, 512, 512, 8);
  final_kernel<<<8192, 256, 0, stream>>>(out_pre, out);
}

// Round 11
// 205.800 us; speedup vs baseline: 1.7171x; 1.7171x over previous
//
#include <hip/hip_runtime.h>
#include <hip/hip_bf16.h>
#include <stdint.h>

// HyperbolicAttention MI355X implementation.
// B=2, N=4096, D_IN=256, UNITS=512, H=8, depth=64.
// Round 11: R9 attention (32x32 MFMA, in-register P via permlane32_swap, j-split x2)
// + full residency (launch_bounds(256,4), grid 1024 = exactly 4 blocks/CU, no tail)
// + ones-MFMA denominator (moves 32 f32 adds/wave-jc from the saturated VALU pipe
//   to the 3x-headroom MFMA pipe; den = accden[0], no cross-lane op).

typedef __attribute__((ext_vector_type(8))) short short8;
typedef __attribute__((ext_vector_type(4))) float f32x4;
typedef __attribute__((ext_vector_type(16))) float f32x16;
typedef __attribute__((ext_vector_type(2))) unsigned int u32x2;
typedef __attribute__((ext_vector_type(4))) unsigned int u32x4;

#define DEVFN static __device__ __forceinline__

DEVFN unsigned short f2bf(float f) {
  unsigned u = __float_as_uint(f);
  u += 0x7FFFu + ((u >> 16) & 1u);   // RNE
  return (unsigned short)(u >> 16);
}

DEVFN void mfma16(f32x4& d, short8 a, short8 b) {
  d = __builtin_amdgcn_mfma_f32_16x16x32_bf16(a, b, d, 0, 0, 0);
}
DEVFN void mfma32(f32x16& d, short8 a, short8 b) {
  d = __builtin_amdgcn_mfma_f32_32x32x16_bf16(a, b, d, 0, 0, 0);
}

DEVFN void gload_lds16(const void* g, void* l) {
  __builtin_amdgcn_global_load_lds((__attribute__((address_space(1))) void*)g,
                                   (__attribute__((address_space(3))) void*)l, 16, 0, 0);
}

// ---------------- weight convert + transpose to BT layout (bf16) ----------------
__global__ __launch_bounds__(256) void wconv_kernel(const float* Wq, const float* Wk,
                                                    const float* Wv, const float* Wo,
                                                    unsigned short* wqkvT, unsigned short* woT) {
  int t = blockIdx.x * 256 + threadIdx.x;
  if (t < 1536 * 256) {
    int nn = t >> 8, kk = t & 255;
    int which = nn >> 9, n2 = nn & 511;
    const float* W = (which == 0) ? Wq : (which == 1) ? Wk : Wv;
    wqkvT[t] = f2bf(W[kk * 512 + n2]);
  }
  int t2 = t - 1536 * 256;
  if (t2 >= 0 && t2 < 512 * 512) {
    int nn = t2 >> 9, kk = t2 & 511;
    woT[t2] = f2bf(Wo[kk * 512 + nn]);
  }
}

// ---------------- tangent = logmap0(inputs), bf16 [8192][256] ----------------
__global__ __launch_bounds__(256) void tangent_kernel(const float* x, unsigned short* tang) {
  const int row = blockIdx.x;
  const int tid = threadIdx.x;
  float v = x[(size_t)row * 256 + tid];
  float ss = v * v;
  #pragma unroll
  for (int m = 1; m <= 32; m <<= 1) ss += __shfl_xor(ss, m, 64);
  __shared__ __align__(16) float red[4];
  if ((tid & 63) == 0) red[tid >> 6] = ss;
  __syncthreads();
  float tot = (red[0] + red[1]) + (red[2] + red[3]);
  float n = fmaxf(sqrtf(tot), 1e-7f);
  float arg = fminf(n, 1.0f - 1e-5f);
  float scale = atanhf(arg) / n;
  tang[(size_t)row * 256 + tid] = f2bf(v * scale);
}

// ---------------- GEMM: C[M][N] f32 = A[M][K]bf16 @ B, B given as BT[N][K]bf16 ----------------
__global__ __launch_bounds__(256) void gemm_bt(const unsigned short* A, const unsigned short* BT,
                                               float* C, int M, int N, int K, int NB) {
  __shared__ __align__(16) unsigned short As[2][64 * 64];
  __shared__ __align__(16) unsigned short Bs[2][64 * 64];
  const int tid = threadIdx.x;
  const int l = tid & 63, w = tid >> 6;
  const int g = l >> 4, i = l & 15;
  const int bm = blockIdx.x / NB, bn = blockIdx.x % NB;
  const int m0 = bm << 6, n0 = bn << 6;
  const int wm = w >> 1, wn = w & 1;
  f32x4 acc[2][2] = {};

  const int NK = K >> 6;
  auto stage = [&](int kc, int bb) {
    const int kb = kc << 6;
    #pragma unroll
    for (int inst = 0; inst < 2; ++inst) {
      int o = (w << 11) + (inst << 10) + (l << 4);
      int row = o >> 7;
      int gG = ((o >> 4) & 7) ^ (row & 7);
      gload_lds16(A + ((size_t)(m0 + row) * K + kb + gG * 8),
                  (char*)&As[bb][0] + (w << 11) + (inst << 10));
      gload_lds16(BT + ((size_t)(n0 + row) * K + kb + gG * 8),
                  (char*)&Bs[bb][0] + (w << 11) + (inst << 10));
    }
  };
  stage(0, 0);
  __syncthreads();
  for (int kc = 0; kc < NK; ++kc) {
    const int bb = kc & 1;
    if (kc + 1 < NK) stage(kc + 1, bb ^ 1);
    #pragma unroll
    for (int hh = 0; hh < 2; ++hh) {
      short8 af[2], bf[2];
      #pragma unroll
      for (int mt = 0; mt < 2; ++mt) {
        int row = (wm << 5) + (mt << 4) + i;
        af[mt] = *(const short8*)((const char*)&As[bb][0] + (row << 7) +
                                  ((((hh << 2) + g) ^ (row & 7)) << 4));
      }
      #pragma unroll
      for (int nt = 0; nt < 2; ++nt) {
        int row = (wn << 5) + (nt << 4) + i;
        bf[nt] = *(const short8*)((const char*)&Bs[bb][0] + (row << 7) +
                                  ((((hh << 2) + g) ^ (row & 7)) << 4));
      }
      #pragma unroll
      for (int mt = 0; mt < 2; ++mt)
        #pragma unroll
        for (int nt = 0; nt < 2; ++nt)
          mfma16(acc[mt][nt], af[mt], bf[nt]);
    }
    __syncthreads();
  }
  #pragma unroll
  for (int mt = 0; mt < 2; ++mt)
    #pragma unroll
    for (int nt = 0; nt < 2; ++nt)
      #pragma unroll
      for (int r = 0; r < 4; ++r) {
        int row = m0 + (wm << 5) + (mt << 4) + (g << 2) + r;
        int col = n0 + (wn << 5) + (nt << 4) + i;
        C[(size_t)row * N + col] = acc[mt][nt][r];
      }
}

// ---------------- per-head hyperbolic maps ----------------
__global__ __launch_bounds__(256) void hyp_kernel(const float* qkv, unsigned short* qh,
                                                  unsigned short* kh, unsigned short* vT,
                                                  float* k2lT) {
  __shared__ __align__(16) unsigned short vt_t[64][72];
  const int tid = threadIdx.x;
  const int l = tid & 63, w = tid >> 6;
  const int bh = blockIdx.x & 15, nt = blockIdx.x >> 4;
  const int b = bh >> 3, h = bh & 7;
  const int n0 = nt << 6;
  const int d = l;
  for (int r = 0; r < 16; ++r) {
    int n = n0 + w * 16 + r;
    size_t base = (size_t)(b * 4096 + n) * 1536 + h * 64 + d;
    float qv = qkv[base], kv = qkv[base + 512], vv = qkv[base + 1024];
    float sq = qv * qv, sk = kv * kv, sv = vv * vv;
    #pragma unroll
    for (int m = 1; m <= 32; m <<= 1) {
      sq += __shfl_xor(sq, m, 64);
      sk += __shfl_xor(sk, m, 64);
      sv += __shfl_xor(sv, m, 64);
    }
    float nq = fmaxf(sqrtf(sq), 1e-7f);
    float qs = tanhf(nq) / nq;
    float nk = fmaxf(sqrtf(sk), 1e-7f);
    float tk = tanhf(nk);
    float ks = tk / nk;
    float nv = fmaxf(sqrtf(sv), 1e-7f);
    float vs = atanhf(fminf(nv, 1.0f - 1e-5f)) / nv;
    size_t ob = (size_t)(b * 4096 + n) * 512 + h * 64 + d;
    qh[ob] = f2bf(qv * qs);
    kh[ob] = f2bf(kv * ks);
    if (d == 0) k2lT[(size_t)bh * 4096 + n] = tk * tk * 0.125f * 1.4426950408889634f;
    vt_t[d][w * 16 + r] = f2bf(vv * vs);
  }
  __syncthreads();
  const int dd = tid >> 2, p = tid & 3;
  u32x4 a0 = *(const u32x4*)&vt_t[dd][p * 16];
  u32x4 a1 = *(const u32x4*)&vt_t[dd][p * 16 + 8];
  size_t vb = (size_t)(bh * 64 + dd) * 4096 + n0 + p * 16;
  *(u32x4*)(vT + vb) = a0;
  *(u32x4*)(vT + vb + 8) = a1;
}

// ---------------- attention (32x32 MFMA, in-register P, j-split) ----------------
// Grid 1024 = (bh[4b], qt[5b], half[1b]); launch_bounds(256,4) -> all 4 blocks/CU
// resident (no tail pass). 4 waves; wave w owns a 32-q strip q = qt*128+w*32+(lane&31).
// Block does j in [half*2048, +2048), 32 jc of 64. K/V staged global->LDS dbuf (32KB,
// XOR-swizzled via source). Swapped QK at 32x32x16: S^T = mfma(K,Q), C: col q=lane&31,
// row j_local = (reg&3)+8*(reg>>2)+4*hi -> each lane holds 16 P values of ONE q.
// PV B-frag in-register: 8 cvt_pk + 4 permlane32_swap (T12, verified R9).
// Denominator via ones-MFMA (A=1): accden[reg] = rowsum of bf16 P for col q — same
// P fragments as the numerator, zero VALU, zero cross-lane; den = accden[0].
// Outputs unnormalized partial O (f32) + den; combine_kernel merges halves.
__global__ __launch_bounds__(256, 4) void attn_kernel(const unsigned short* __restrict__ qhG,
                                                      const unsigned short* __restrict__ khG,
                                                      const unsigned short* __restrict__ vTG,
                                                      const float* __restrict__ k2lG,
                                                      float* __restrict__ opart,
                                                      float* __restrict__ denpart) {
  __shared__ __align__(16) unsigned short Kbuf[2][64 * 64];
  __shared__ __align__(16) unsigned short Vbuf[2][64 * 64];

  const int tid = threadIdx.x;
  const int lane = tid & 63, w = tid >> 6;
  const int l31 = lane & 31, hi = lane >> 5;
  const int p = blockIdx.x;
  const int bh = p & 15, qt = (p >> 4) & 31, half = p >> 9;
  const int b = bh >> 3, h = bh & 7;
  const int qw = qt * 128 + w * 32;
  const int j0 = half * 2048;

  const float CQK = 0.36067376022224087f;  // 0.25 * log2(e)
  const short8 ONES = {16256, 16256, 16256, 16256, 16256, 16256, 16256, 16256};  // bf16 1.0

  // resident Q B-frags: col q = qw + l31, k-elem d = kk*16 + hi*8 + e
  short8 qf[4];
  #pragma unroll
  for (int kk = 0; kk < 4; ++kk)
    qf[kk] = *(const short8*)(qhG + (size_t)(b * 4096 + qw + l31) * 512 +
                              h * 64 + kk * 16 + hi * 8);

  f32x16 acc[2] = {};    // [dh]: O^T rows d = dh*32 + (reg&3)+8*(reg>>2)+4*hi, col q
  f32x16 accden = {};    // rowsum of P per col q (all regs equal at the end)

  auto stage = [&](int jc2, int bb) {
    const int jb = jc2 << 6;
    #pragma unroll
    for (int inst = 0; inst < 2; ++inst) {
      int o = (w << 11) + (inst << 10) + (lane << 4);
      int row = o >> 7;
      int gG = ((o >> 4) & 7) ^ (row & 7);
      gload_lds16(khG + ((size_t)(b * 4096 + j0 + jb + row) * 512 + h * 64 + gG * 8),
                  (char*)&Kbuf[bb][0] + o);
      gload_lds16(vTG + ((size_t)(bh * 64 + row) * 4096 + j0 + jb + gG * 8),
                  (char*)&Vbuf[bb][0] + o);
    }
  };

  stage(0, 0);
  __syncthreads();

  const float* k2b = k2lG + (size_t)bh * 4096 + j0;

  for (int jc = 0; jc < 32; ++jc) {
    const int bb = jc & 1;
    if (jc + 1 < 32) stage(jc + 1, bb ^ 1);
    const char* Kb = (const char*)&Kbuf[bb][0];
    const char* Vb = (const char*)&Vbuf[bb][0];

    #pragma unroll
    for (int js = 0; js < 2; ++js) {
      // QK^T: A = K rows j = js*32 + l31, k d = kk*16 + hi*8 + e
      const int krow = js * 32 + l31;
      const int ksw = krow & 7;
      f32x16 S = {};
      #pragma unroll
      for (int kk = 0; kk < 4; ++kk) {
        short8 kf = *(const short8*)(Kb + (krow << 7) + ((((kk << 1) + hi) ^ ksw) << 4));
        mfma32(S, kf, qf[kk]);
      }
      // p = exp2(S*CQK - k2l[j]); j_local(reg) = (reg&3) + 8*(reg>>2) + 4*hi
      const float* k2p = k2b + (jc << 6) + js * 32 + hi * 4;
      float pr[16];
      #pragma unroll
      for (int t = 0; t < 4; ++t) {
        f32x4 k2v = *(const f32x4*)(k2p + t * 8);
        #pragma unroll
        for (int e = 0; e < 4; ++e)
          pr[t * 4 + e] = __builtin_amdgcn_exp2f(fmaf(S[t * 4 + e], CQK, -k2v[e]));
      }
      // pack pairs: wds[m] = bf16x2(pr[2m], pr[2m+1])
      unsigned wds[8];
      #pragma unroll
      for (int m = 0; m < 8; ++m) {
        __hip_bfloat162 t2 = __float22bfloat162_rn(make_float2(pr[2 * m], pr[2 * m + 1]));
        __builtin_memcpy(&wds[m], &t2, 4);
      }
      // T12: swap(word m, word m+2) -> [0]=frag word m, [1]=frag word m+2
      u32x2 s0 = __builtin_amdgcn_permlane32_swap(wds[0], wds[2], false, false);
      u32x2 s1 = __builtin_amdgcn_permlane32_swap(wds[1], wds[3], false, false);
      u32x2 s2 = __builtin_amdgcn_permlane32_swap(wds[4], wds[6], false, false);
      u32x2 s3 = __builtin_amdgcn_permlane32_swap(wds[5], wds[7], false, false);
      unsigned fw[2][4];
      fw[0][0] = s0[0]; fw[0][1] = s1[0]; fw[0][2] = s0[1]; fw[0][3] = s1[1];
      fw[1][0] = s2[0]; fw[1][1] = s3[0]; fw[1][2] = s2[1]; fw[1][3] = s3[1];
      // PV: A = V^T rows d = dh*32 + l31, k j = js*32 + kc2*16 + hi*8 + e; B = P^T
      // den: A = ones -> rowsum of same P fragments (MFMA pipe, no VALU)
      #pragma unroll
      for (int kc2 = 0; kc2 < 2; ++kc2) {
        u32x4 t4;
        t4[0] = fw[kc2][0];
        t4[1] = fw[kc2][1];
        t4[2] = fw[kc2][2];
        t4[3] = fw[kc2][3];
        short8 pf;
        __builtin_memcpy(&pf, &t4, 16);
        mfma32(accden, ONES, pf);
        #pragma unroll
        for (int dh = 0; dh < 2; ++dh) {
          const int vrow = dh * 32 + l31;
          const int gv = ((js << 2) + (kc2 << 1) + hi) ^ (vrow & 7);
          short8 vf = *(const short8*)(Vb + (vrow << 7) + (gv << 4));
          mfma32(acc[dh], vf, pf);
        }
      }
    }
    __syncthreads();
  }

  // partial epilogue: unnormalized O (f32) + row denominators
  float* ob = opart + (size_t)half * (8192 * 512);
  const size_t obase = (size_t)(b * 4096 + qw + l31) * 512 + h * 64;
  #pragma unroll
  for (int dh = 0; dh < 2; ++dh)
    #pragma unroll
    for (int reg = 0; reg < 16; ++reg) {
      int d = dh * 32 + (reg & 3) + 8 * (reg >> 2) + 4 * hi;
      ob[obase + d] = acc[dh][reg];
    }
  if (lane < 32)
    denpart[half * 65536 + bh * 4096 + qw + l31] = accden[0];
}

// ---------------- combine: ctx = (O0+O1) / (d0+d1), bf16 ----------------
__global__ __launch_bounds__(256) void combine_kernel(const float* __restrict__ opart,
                                                      const float* __restrict__ denpart,
                                                      unsigned short* __restrict__ ctx) {
  const int idx = blockIdx.x * 256 + threadIdx.x;   // 1,048,576 f32x4 groups
  const int row = idx >> 7;
  const int g4 = (idx & 127) << 2;
  const int b = row >> 12, q = row & 4095;
  const int bh = b * 8 + (g4 >> 6);
  const float den = denpart[bh * 4096 + q] + denpart[65536 + bh * 4096 + q];
  const float inv = 1.0f / den;
  const size_t off = (size_t)row * 512 + g4;
  f32x4 o0 = *(const f32x4*)(opart + off);
  f32x4 o1 = *(const f32x4*)(opart + 4194304 + off);
  __hip_bfloat162 lo = __float22bfloat162_rn(make_float2((o0[0] + o1[0]) * inv,
                                                         (o0[1] + o1[1]) * inv));
  __hip_bfloat162 hi = __float22bfloat162_rn(make_float2((o0[2] + o1[2]) * inv,
                                                         (o0[3] + o1[3]) * inv));
  unsigned lo_u, hi_u;
  __builtin_memcpy(&lo_u, &lo, 4);
  __builtin_memcpy(&hi_u, &hi, 4);
  u32x2 pk;
  pk[0] = lo_u;
  pk[1] = hi_u;
  *(u32x2*)(ctx + off) = pk;
}

// ---------------- final expmap0 over 512-dim rows ----------------
__global__ __launch_bounds__(256) void final_kernel(const float* xin, float* out) {
  const int row = blockIdx.x;
  const int tid = threadIdx.x;
  const float* xr = xin + (size_t)row * 512;
  float v0 = xr[tid], v1 = xr[tid + 256];
  float ss = v0 * v0 + v1 * v1;
  #pragma unroll
  for (int m = 1; m <= 32; m <<= 1) ss += __shfl_xor(ss, m, 64);
  __shared__ __align__(16) float red[4];
  if ((tid & 63) == 0) red[tid >> 6] = ss;
  __syncthreads();
  float tot = (red[0] + red[1]) + (red[2] + red[3]);
  float n = fmaxf(sqrtf(tot), 1e-7f);
  float sc = tanhf(n) / n;
  out[(size_t)row * 512 + tid] = v0 * sc;
  out[(size_t)row * 512 + tid + 256] = v1 * sc;
}

// ---------------- launch ----------------
extern "C" void kernel_launch(void* const* d_in, const int* in_sizes, int n_in,
                              void* d_out, int out_size, void* d_ws, size_t ws_size,
                              hipStream_t stream) {
  const float* inputs = (const float*)d_in[0];
  const float* Wq = (const float*)d_in[1];
  const float* Wk = (const float*)d_in[2];
  const float* Wv = (const float*)d_in[3];
  const float* Wo = (const float*)d_in[4];
  float* out = (float*)d_out;
  char* ws = (char*)d_ws;

  // workspace layout (~79.25 MB peak):
  //  [0,48M):  qkv f32 [8192][1536] during proj; after hyp dead. Reuse:
  //    ctx bf16 @0 (8M); opart f32 [2][8192][512] @8M (32M, dead after combine);
  //    out_pre f32 @8M (16M, written after combine over dead opart)
  //  [48M): k2lT f32 (256K); [49M): denpart f32 [2][65536] (512K)
  //  [53M): wqkvT (0.75M); [54M): woT (0.5M)
  //  [55M): qh (8M); [63M): kh (8M); [71M): vT (8M)    (tang @48M during proj)
  float* qkv            = (float*)(ws);
  unsigned short* ctx   = (unsigned short*)(ws);
  float* opart          = (float*)(ws + ((size_t)8 << 20));
  float* out_pre        = (float*)(ws + ((size_t)8 << 20));
  unsigned short* tang  = (unsigned short*)(ws + ((size_t)48 << 20));
  float* k2lT           = (float*)(ws + ((size_t)48 << 20));
  float* denpart        = (float*)(ws + ((size_t)49 << 20));
  unsigned short* wqkvT = (unsigned short*)(ws + ((size_t)53 << 20));
  unsigned short* woT   = (unsigned short*)(ws + ((size_t)54 << 20));
  unsigned short* qh    = (unsigned short*)(ws + ((size_t)55 << 20));
  unsigned short* kh    = (unsigned short*)(ws + ((size_t)63 << 20));
  unsigned short* vT    = (unsigned short*)(ws + ((size_t)71 << 20));

  wconv_kernel<<<2560, 256, 0, stream>>>(Wq, Wk, Wv, Wo, wqkvT, woT);
  tangent_kernel<<<8192, 256, 0, stream>>>(inputs, tang);
  gemm_bt<<<128 * 24, 256, 0, stream>>>(tang, wqkvT, qkv, 8192, 1536, 256, 24);
  hyp_kernel<<<1024, 256, 0, stream>>>(qkv, qh, kh, vT, k2lT);
  attn_kernel<<<1024, 256, 0, stream>>>(qh, kh, vT, k2lT, opart, denpart);
  combine_kernel<<<4096, 256, 0, stream>>>(opart, denpart, ctx);
  gemm_bt<<<128 * 8, 256, 0, stream>>>(ctx, woT, out_pre, 8192, 512, 512, 8);
  final_kernel<<<8192, 256, 0, stream>>>(out_pre, out);
}

// Round 13
// 202.272 us; speedup vs baseline: 1.7471x; 1.0174x over previous
//
#include <hip/hip_runtime.h>
#include <hip/hip_bf16.h>
#include <stdint.h>

// HyperbolicAttention MI355X implementation.
// B=2, N=4096, D_IN=256, UNITS=512, H=8, depth=64.
// Round 13: R12 (128x128-tile GEMMs, bf16 qkv) with the workspace-aliasing bug fixed:
// tang back at 48M ([48,52M), dead after gemm1) — R12 had it at 50M, clobbering wqkvT@53M.

typedef __attribute__((ext_vector_type(8))) short short8;
typedef __attribute__((ext_vector_type(4))) float f32x4;
typedef __attribute__((ext_vector_type(16))) float f32x16;
typedef __attribute__((ext_vector_type(2))) unsigned int u32x2;
typedef __attribute__((ext_vector_type(4))) unsigned int u32x4;

#define DEVFN static __device__ __forceinline__

DEVFN unsigned short f2bf(float f) {
  unsigned u = __float_as_uint(f);
  u += 0x7FFFu + ((u >> 16) & 1u);   // RNE
  return (unsigned short)(u >> 16);
}
DEVFN float bf2f(unsigned short u) {
  return __uint_as_float(((unsigned)u) << 16);
}

DEVFN void mfma16(f32x4& d, short8 a, short8 b) {
  d = __builtin_amdgcn_mfma_f32_16x16x32_bf16(a, b, d, 0, 0, 0);
}
DEVFN void mfma32(f32x16& d, short8 a, short8 b) {
  d = __builtin_amdgcn_mfma_f32_32x32x16_bf16(a, b, d, 0, 0, 0);
}

DEVFN void gload_lds16(const void* g, void* l) {
  __builtin_amdgcn_global_load_lds((__attribute__((address_space(1))) void*)g,
                                   (__attribute__((address_space(3))) void*)l, 16, 0, 0);
}

// ---------------- weight convert + transpose to BT layout (bf16) ----------------
__global__ __launch_bounds__(256) void wconv_kernel(const float* Wq, const float* Wk,
                                                    const float* Wv, const float* Wo,
                                                    unsigned short* wqkvT, unsigned short* woT) {
  int t = blockIdx.x * 256 + threadIdx.x;
  if (t < 1536 * 256) {
    int nn = t >> 8, kk = t & 255;
    int which = nn >> 9, n2 = nn & 511;
    const float* W = (which == 0) ? Wq : (which == 1) ? Wk : Wv;
    wqkvT[t] = f2bf(W[kk * 512 + n2]);
  }
  int t2 = t - 1536 * 256;
  if (t2 >= 0 && t2 < 512 * 512) {
    int nn = t2 >> 9, kk = t2 & 511;
    woT[t2] = f2bf(Wo[kk * 512 + nn]);
  }
}

// ---------------- tangent = logmap0(inputs), bf16 [8192][256] ----------------
__global__ __launch_bounds__(256) void tangent_kernel(const float* x, unsigned short* tang) {
  const int row = blockIdx.x;
  const int tid = threadIdx.x;
  float v = x[(size_t)row * 256 + tid];
  float ss = v * v;
  #pragma unroll
  for (int m = 1; m <= 32; m <<= 1) ss += __shfl_xor(ss, m, 64);
  __shared__ __align__(16) float red[4];
  if ((tid & 63) == 0) red[tid >> 6] = ss;
  __syncthreads();
  float tot = (red[0] + red[1]) + (red[2] + red[3]);
  float n = fmaxf(sqrtf(tot), 1e-7f);
  float arg = fminf(n, 1.0f - 1e-5f);
  float scale = atanhf(arg) / n;
  tang[(size_t)row * 256 + tid] = f2bf(v * scale);
}

// ---------------- GEMM 128x128: C[M][N] = A[M][K]bf16 @ BT[N][K]bf16 ----------------
// m93/m97 ladder structure: 256 threads = 4 waves in 2x2, each wave owns a 64x64
// quadrant (4x4 16x16 frags), BK=64, 64KB LDS dbuf, gload_lds16 with XOR-swizzled
// source, swizzled b128 frag reads. Output templated: f32 or bf16.
template <bool BF16OUT>
__global__ __launch_bounds__(256) void gemm_bt128(const unsigned short* A,
                                                  const unsigned short* BT,
                                                  void* Cv, int M, int N, int K, int NB) {
  __shared__ __align__(16) unsigned short As[2][128 * 64];
  __shared__ __align__(16) unsigned short Bs[2][128 * 64];
  const int tid = threadIdx.x;
  const int l = tid & 63, w = tid >> 6;
  const int g = l >> 4, i = l & 15;
  const int bm = blockIdx.x / NB, bn = blockIdx.x % NB;
  const int m0 = bm << 7, n0 = bn << 7;
  const int wm = w >> 1, wn = w & 1;
  f32x4 acc[4][4] = {};

  const int NK = K >> 6;
  auto stage = [&](int kc, int bb) {
    const int kb = kc << 6;
    #pragma unroll
    for (int inst = 0; inst < 4; ++inst) {
      int o = (tid << 4) + (inst << 12);
      int row = o >> 7;
      int gG = ((o >> 4) & 7) ^ (row & 7);
      gload_lds16(A + ((size_t)(m0 + row) * K + kb + gG * 8), (char*)&As[bb][0] + o);
      gload_lds16(BT + ((size_t)(n0 + row) * K + kb + gG * 8), (char*)&Bs[bb][0] + o);
    }
  };
  stage(0, 0);
  __syncthreads();
  for (int kc = 0; kc < NK; ++kc) {
    const int bb = kc & 1;
    if (kc + 1 < NK) stage(kc + 1, bb ^ 1);
    #pragma unroll
    for (int hh = 0; hh < 2; ++hh) {
      short8 af[4], bf[4];
      #pragma unroll
      for (int mt = 0; mt < 4; ++mt) {
        int row = (wm << 6) + (mt << 4) + i;
        af[mt] = *(const short8*)((const char*)&As[bb][0] + (row << 7) +
                                  ((((hh << 2) + g) ^ (row & 7)) << 4));
      }
      #pragma unroll
      for (int nt = 0; nt < 4; ++nt) {
        int row = (wn << 6) + (nt << 4) + i;
        bf[nt] = *(const short8*)((const char*)&Bs[bb][0] + (row << 7) +
                                  ((((hh << 2) + g) ^ (row & 7)) << 4));
      }
      #pragma unroll
      for (int mt = 0; mt < 4; ++mt)
        #pragma unroll
        for (int nt = 0; nt < 4; ++nt)
          mfma16(acc[mt][nt], af[mt], bf[nt]);
    }
    __syncthreads();
  }
  #pragma unroll
  for (int mt = 0; mt < 4; ++mt)
    #pragma unroll
    for (int nt = 0; nt < 4; ++nt)
      #pragma unroll
      for (int r = 0; r < 4; ++r) {
        int row = m0 + (wm << 6) + (mt << 4) + (g << 2) + r;
        int col = n0 + (wn << 6) + (nt << 4) + i;
        if (BF16OUT)
          ((unsigned short*)Cv)[(size_t)row * N + col] = f2bf(acc[mt][nt][r]);
        else
          ((float*)Cv)[(size_t)row * N + col] = acc[mt][nt][r];
      }
}

// ---------------- per-head hyperbolic maps (qkv bf16) ----------------
__global__ __launch_bounds__(256) void hyp_kernel(const unsigned short* qkv, unsigned short* qh,
                                                  unsigned short* kh, unsigned short* vT,
                                                  float* k2lT) {
  __shared__ __align__(16) unsigned short vt_t[64][72];
  const int tid = threadIdx.x;
  const int l = tid & 63, w = tid >> 6;
  const int bh = blockIdx.x & 15, nt = blockIdx.x >> 4;
  const int b = bh >> 3, h = bh & 7;
  const int n0 = nt << 6;
  const int d = l;
  for (int r = 0; r < 16; ++r) {
    int n = n0 + w * 16 + r;
    size_t base = (size_t)(b * 4096 + n) * 1536 + h * 64 + d;
    float qv = bf2f(qkv[base]), kv = bf2f(qkv[base + 512]), vv = bf2f(qkv[base + 1024]);
    float sq = qv * qv, sk = kv * kv, sv = vv * vv;
    #pragma unroll
    for (int m = 1; m <= 32; m <<= 1) {
      sq += __shfl_xor(sq, m, 64);
      sk += __shfl_xor(sk, m, 64);
      sv += __shfl_xor(sv, m, 64);
    }
    float nq = fmaxf(sqrtf(sq), 1e-7f);
    float qs = tanhf(nq) / nq;
    float nk = fmaxf(sqrtf(sk), 1e-7f);
    float tk = tanhf(nk);
    float ks = tk / nk;
    float nv = fmaxf(sqrtf(sv), 1e-7f);
    float vs = atanhf(fminf(nv, 1.0f - 1e-5f)) / nv;
    size_t ob = (size_t)(b * 4096 + n) * 512 + h * 64 + d;
    qh[ob] = f2bf(qv * qs);
    kh[ob] = f2bf(kv * ks);
    if (d == 0) k2lT[(size_t)bh * 4096 + n] = tk * tk * 0.125f * 1.4426950408889634f;
    vt_t[d][w * 16 + r] = f2bf(vv * vs);
  }
  __syncthreads();
  const int dd = tid >> 2, p = tid & 3;
  u32x4 a0 = *(const u32x4*)&vt_t[dd][p * 16];
  u32x4 a1 = *(const u32x4*)&vt_t[dd][p * 16 + 8];
  size_t vb = (size_t)(bh * 64 + dd) * 4096 + n0 + p * 16;
  *(u32x4*)(vT + vb) = a0;
  *(u32x4*)(vT + vb + 8) = a1;
}

// ---------------- attention (R11, unchanged) ----------------
__global__ __launch_bounds__(256, 4) void attn_kernel(const unsigned short* __restrict__ qhG,
                                                      const unsigned short* __restrict__ khG,
                                                      const unsigned short* __restrict__ vTG,
                                                      const float* __restrict__ k2lG,
                                                      float* __restrict__ opart,
                                                      float* __restrict__ denpart) {
  __shared__ __align__(16) unsigned short Kbuf[2][64 * 64];
  __shared__ __align__(16) unsigned short Vbuf[2][64 * 64];

  const int tid = threadIdx.x;
  const int lane = tid & 63, w = tid >> 6;
  const int l31 = lane & 31, hi = lane >> 5;
  const int p = blockIdx.x;
  const int bh = p & 15, qt = (p >> 4) & 31, half = p >> 9;
  const int b = bh >> 3, h = bh & 7;
  const int qw = qt * 128 + w * 32;
  const int j0 = half * 2048;

  const float CQK = 0.36067376022224087f;  // 0.25 * log2(e)
  const short8 ONES = {16256, 16256, 16256, 16256, 16256, 16256, 16256, 16256};  // bf16 1.0

  short8 qf[4];
  #pragma unroll
  for (int kk = 0; kk < 4; ++kk)
    qf[kk] = *(const short8*)(qhG + (size_t)(b * 4096 + qw + l31) * 512 +
                              h * 64 + kk * 16 + hi * 8);

  f32x16 acc[2] = {};
  f32x16 accden = {};

  auto stage = [&](int jc2, int bb) {
    const int jb = jc2 << 6;
    #pragma unroll
    for (int inst = 0; inst < 2; ++inst) {
      int o = (w << 11) + (inst << 10) + (lane << 4);
      int row = o >> 7;
      int gG = ((o >> 4) & 7) ^ (row & 7);
      gload_lds16(khG + ((size_t)(b * 4096 + j0 + jb + row) * 512 + h * 64 + gG * 8),
                  (char*)&Kbuf[bb][0] + o);
      gload_lds16(vTG + ((size_t)(bh * 64 + row) * 4096 + j0 + jb + gG * 8),
                  (char*)&Vbuf[bb][0] + o);
    }
  };

  stage(0, 0);
  __syncthreads();

  const float* k2b = k2lG + (size_t)bh * 4096 + j0;

  for (int jc = 0; jc < 32; ++jc) {
    const int bb = jc & 1;
    if (jc + 1 < 32) stage(jc + 1, bb ^ 1);
    const char* Kb = (const char*)&Kbuf[bb][0];
    const char* Vb = (const char*)&Vbuf[bb][0];

    #pragma unroll
    for (int js = 0; js < 2; ++js) {
      const int krow = js * 32 + l31;
      const int ksw = krow & 7;
      f32x16 S = {};
      #pragma unroll
      for (int kk = 0; kk < 4; ++kk) {
        short8 kf = *(const short8*)(Kb + (krow << 7) + ((((kk << 1) + hi) ^ ksw) << 4));
        mfma32(S, kf, qf[kk]);
      }
      const float* k2p = k2b + (jc << 6) + js * 32 + hi * 4;
      float pr[16];
      #pragma unroll
      for (int t = 0; t < 4; ++t) {
        f32x4 k2v = *(const f32x4*)(k2p + t * 8);
        #pragma unroll
        for (int e = 0; e < 4; ++e)
          pr[t * 4 + e] = __builtin_amdgcn_exp2f(fmaf(S[t * 4 + e], CQK, -k2v[e]));
      }
      unsigned wds[8];
      #pragma unroll
      for (int m = 0; m < 8; ++m) {
        __hip_bfloat162 t2 = __float22bfloat162_rn(make_float2(pr[2 * m], pr[2 * m + 1]));
        __builtin_memcpy(&wds[m], &t2, 4);
      }
      u32x2 s0 = __builtin_amdgcn_permlane32_swap(wds[0], wds[2], false, false);
      u32x2 s1 = __builtin_amdgcn_permlane32_swap(wds[1], wds[3], false, false);
      u32x2 s2 = __builtin_amdgcn_permlane32_swap(wds[4], wds[6], false, false);
      u32x2 s3 = __builtin_amdgcn_permlane32_swap(wds[5], wds[7], false, false);
      unsigned fw[2][4];
      fw[0][0] = s0[0]; fw[0][1] = s1[0]; fw[0][2] = s0[1]; fw[0][3] = s1[1];
      fw[1][0] = s2[0]; fw[1][1] = s3[0]; fw[1][2] = s2[1]; fw[1][3] = s3[1];
      #pragma unroll
      for (int kc2 = 0; kc2 < 2; ++kc2) {
        u32x4 t4;
        t4[0] = fw[kc2][0];
        t4[1] = fw[kc2][1];
        t4[2] = fw[kc2][2];
        t4[3] = fw[kc2][3];
        short8 pf;
        __builtin_memcpy(&pf, &t4, 16);
        mfma32(accden, ONES, pf);
        #pragma unroll
        for (int dh = 0; dh < 2; ++dh) {
          const int vrow = dh * 32 + l31;
          const int gv = ((js << 2) + (kc2 << 1) + hi) ^ (vrow & 7);
          short8 vf = *(const short8*)(Vb + (vrow << 7) + (gv << 4));
          mfma32(acc[dh], vf, pf);
        }
      }
    }
    __syncthreads();
  }

  float* ob = opart + (size_t)half * (8192 * 512);
  const size_t obase = (size_t)(b * 4096 + qw + l31) * 512 + h * 64;
  #pragma unroll
  for (int dh = 0; dh < 2; ++dh)
    #pragma unroll
    for (int reg = 0; reg < 16; ++reg) {
      int d = dh * 32 + (reg & 3) + 8 * (reg >> 2) + 4 * hi;
      ob[obase + d] = acc[dh][reg];
    }
  if (lane < 32)
    denpart[half * 65536 + bh * 4096 + qw + l31] = accden[0];
}

// ---------------- combine: ctx = (O0+O1) / (d0+d1), bf16 ----------------
__global__ __launch_bounds__(256) void combine_kernel(const float* __restrict__ opart,
                                                      const float* __restrict__ denpart,
                                                      unsigned short* __restrict__ ctx) {
  const int idx = blockIdx.x * 256 + threadIdx.x;   // 1,048,576 f32x4 groups
  const int row = idx >> 7;
  const int g4 = (idx & 127) << 2;
  const int b = row >> 12, q = row & 4095;
  const int bh = b * 8 + (g4 >> 6);
  const float den = denpart[bh * 4096 + q] + denpart[65536 + bh * 4096 + q];
  const float inv = 1.0f / den;
  const size_t off = (size_t)row * 512 + g4;
  f32x4 o0 = *(const f32x4*)(opart + off);
  f32x4 o1 = *(const f32x4*)(opart + 4194304 + off);
  __hip_bfloat162 lo = __float22bfloat162_rn(make_float2((o0[0] + o1[0]) * inv,
                                                         (o0[1] + o1[1]) * inv));
  __hip_bfloat162 hi = __float22bfloat162_rn(make_float2((o0[2] + o1[2]) * inv,
                                                         (o0[3] + o1[3]) * inv));
  unsigned lo_u, hi_u;
  __builtin_memcpy(&lo_u, &lo, 4);
  __builtin_memcpy(&hi_u, &hi, 4);
  u32x2 pk;
  pk[0] = lo_u;
  pk[1] = hi_u;
  *(u32x2*)(ctx + off) = pk;
}

// ---------------- final expmap0 over 512-dim rows ----------------
__global__ __launch_bounds__(256) void final_kernel(const float* xin, float* out) {
  const int row = blockIdx.x;
  const int tid = threadIdx.x;
  const float* xr = xin + (size_t)row * 512;
  float v0 = xr[tid], v1 = xr[tid + 256];
  float ss = v0 * v0 + v1 * v1;
  #pragma unroll
  for (int m = 1; m <= 32; m <<= 1) ss += __shfl_xor(ss, m, 64);
  __shared__ __align__(16) float red[4];
  if ((tid & 63) == 0) red[tid >> 6] = ss;
  __syncthreads();
  float tot = (red[0] + red[1]) + (red[2] + red[3]);
  float n = fmaxf(sqrtf(tot), 1e-7f);
  float sc = tanhf(n) / n;
  out[(size_t)row * 512 + tid] = v0 * sc;
  out[(size_t)row * 512 + tid + 256] = v1 * sc;
}

// ---------------- launch ----------------
extern "C" void kernel_launch(void* const* d_in, const int* in_sizes, int n_in,
                              void* d_out, int out_size, void* d_ws, size_t ws_size,
                              hipStream_t stream) {
  const float* inputs = (const float*)d_in[0];
  const float* Wq = (const float*)d_in[1];
  const float* Wk = (const float*)d_in[2];
  const float* Wv = (const float*)d_in[3];
  const float* Wo = (const float*)d_in[4];
  float* out = (float*)d_out;
  char* ws = (char*)d_ws;

  // workspace layout (~79.25 MB peak):
  //  [0,24M):  qkv bf16 [8192][1536] during proj; dead after hyp. Reuse:
  //    ctx bf16 @0 (8M); opart f32 [2][8192][512] @8M (32M, dead after combine);
  //    out_pre f32 @8M (16M, written by gemm2 after combine over dead opart)
  //  [48M,52M): tang bf16 (4M) during proj; dead after gemm1. Aliased (by ordering):
  //    k2lT f32 @48M (256K, written by hyp) + denpart f32 @49M (512K, written by attn)
  //  [53M): wqkvT (0.75M); [54M): woT (0.5M)
  //  [55M): qh (8M); [63M): kh (8M); [71M): vT (8M)
  unsigned short* qkv   = (unsigned short*)(ws);
  unsigned short* ctx   = (unsigned short*)(ws);
  float* opart          = (float*)(ws + ((size_t)8 << 20));
  float* out_pre        = (float*)(ws + ((size_t)8 << 20));
  unsigned short* tang  = (unsigned short*)(ws + ((size_t)48 << 20));
  float* k2lT           = (float*)(ws + ((size_t)48 << 20));
  float* denpart        = (float*)(ws + ((size_t)49 << 20));
  unsigned short* wqkvT = (unsigned short*)(ws + ((size_t)53 << 20));
  unsigned short* woT   = (unsigned short*)(ws + ((size_t)54 << 20));
  unsigned short* qh    = (unsigned short*)(ws + ((size_t)55 << 20));
  unsigned short* kh    = (unsigned short*)(ws + ((size_t)63 << 20));
  unsigned short* vT    = (unsigned short*)(ws + ((size_t)71 << 20));

  wconv_kernel<<<2560, 256, 0, stream>>>(Wq, Wk, Wv, Wo, wqkvT, woT);
  tangent_kernel<<<8192, 256, 0, stream>>>(inputs, tang);
  gemm_bt128<true><<<64 * 12, 256, 0, stream>>>(tang, wqkvT, qkv, 8192, 1536, 256, 12);
  hyp_kernel<<<1024, 256, 0, stream>>>(qkv, qh, kh, vT, k2lT);
  attn_kernel<<<1024, 256, 0, stream>>>(qh, kh, vT, k2lT, opart, denpart);
  combine_kernel<<<4096, 256, 0, stream>>>(opart, denpart, ctx);
  gemm_bt128<false><<<64 * 4, 256, 0, stream>>>(ctx, woT, out_pre, 8192, 512, 512, 4);
  final_kernel<<<8192, 256, 0, stream>>>(out_pre, out);
}